// Round 2
// baseline (410.466 us; speedup 1.0000x reference)
//
#include <hip/hip_runtime.h>

#define BATCH 128
#define NBOX 8732
#define NC 21
#define M (BATCH * NBOX)          // 1,117,696 (divisible by 256 -> no tail)
#define CLIP_MAX 16.118095651f    // -log(1e-7)

struct Ctl {
  float num_pos[BATCH];           // per-batch positive counts
  float pos_conf_sum, pos_loc_sum;
  float s_gt;                     // accumulated conf_loss strictly above threshold
  float s_eq;                     // conf_loss sum of bit-exact ties
  float denom;                    // sum num_pos_c
  unsigned int k_rem;             // remaining rank within current radix bin
  unsigned int prefix;            // accumulated threshold bits
  unsigned int n_eq;              // count of elements equal to threshold
  unsigned int done;              // k == 0 flag (defensive; cannot occur)
  unsigned int pad[7];
  unsigned int hist[2048];        // radix counts (L1 uses [0,1024))
  float        hsum[2048];        // radix conf_loss sums
};

// ---------------------------------------------------------------------------
// Pass 1: LDS-staged fused elementwise (softmax CE via LSE, smooth-L1,
// pos-weighted sums) + level-1 radix histogram (count + CL-sum).
// Block = 256 threads = 256 rows.
// ---------------------------------------------------------------------------
__global__ __launch_bounds__(256) void k_elem(
    const float* __restrict__ yt, const float* __restrict__ lp,
    const float* __restrict__ cp, float* __restrict__ MC,
    float* __restrict__ CL, Ctl* __restrict__ ctl) {
  __shared__ float s_yt[256 * 26];          // 26624 B
  __shared__ float s_cp[256 * 21];          // 21504 B
  __shared__ unsigned int h[1024];          // 4096 B
  __shared__ float hs[1024];                // 4096 B
  __shared__ float sred[16];                // ~56.3 KB total -> 2 blocks/CU

  const int tid = threadIdx.x;
  const int r0 = blockIdx.x * 256;

  // ---- coalesced float4 staging (bases are 16B-aligned: 256*104, 256*84 % 16 == 0)
  const float4* gy = (const float4*)(yt + (size_t)r0 * 26);
  float4* sy = (float4*)s_yt;
  for (int i = tid; i < 1664; i += 256) sy[i] = gy[i];     // 256*26/4
  const float4* gc = (const float4*)(cp + (size_t)r0 * 21);
  float4* sc = (float4*)s_cp;
  for (int i = tid; i < 1344; i += 256) sc[i] = gc[i];     // 256*21/4
  for (int i = tid; i < 1024; i += 256) { h[i] = 0u; hs[i] = 0.f; }
  __syncthreads();

  const int e = r0 + tid;
  const float* y = s_yt + tid * 26;   // lane stride 26 words: 2-way bank alias (free)
  const float* c = s_cp + tid * 21;   // stride 21: conflict-free
  const float4 lv = ((const float4*)lp)[e];   // loc_pred row = one aligned float4
  const float pos = y[25];

  // smooth-L1 loc loss
  float ll = 0.f;
  {
    float d0 = y[0] - lv.x, d1 = y[1] - lv.y, d2 = y[2] - lv.z, d3 = y[3] - lv.w;
    float a0 = fabsf(d0), a1 = fabsf(d1), a2 = fabsf(d2), a3 = fabsf(d3);
    ll += (a0 < 1.f) ? 0.5f * d0 * d0 : a0 - 0.5f;
    ll += (a1 < 1.f) ? 0.5f * d1 * d1 : a1 - 0.5f;
    ll += (a2 < 1.f) ? 0.5f * d2 * d2 : a2 - 0.5f;
    ll += (a3 < 1.f) ? 0.5f * d3 * d3 : a3 - 0.5f;
  }

  // softmax statistics — all static indexing (no scratch)
  float xv[NC];
  float mx = -1e30f;
#pragma unroll
  for (int j = 0; j < NC; ++j) { xv[j] = c[j]; mx = fmaxf(mx, xv[j]); }
  float plogit = 0.f;                      // one-hot selects the label logit exactly
#pragma unroll
  for (int j = 0; j < NC; ++j) plogit = fmaf(y[4 + j], xv[j], plogit);
  float ssum = 0.f, e0 = 0.f;
#pragma unroll
  for (int j = 0; j < NC; ++j) {
    float ee = __expf(xv[j] - mx);
    ssum += ee;
    if (j == 0) e0 = ee;
  }
  // -log(clip(softmax[label],1e-7)) == min(mx + log(s) - logit, -log(1e-7))
  const float cl = fminf(mx + __logf(ssum) - plogit, CLIP_MAX);
  const float mc = (1.f - pos) * ((ssum - e0) / ssum);   // (1-pos)*sum(conf[1:])

  MC[e] = mc;
  CL[e] = cl;

  const unsigned int bin = __float_as_uint(mc) >> 22;    // level-1: top 10 bits
  atomicAdd(&h[bin], 1u);
  atomicAdd(&hs[bin], cl);
  if (pos > 0.f) atomicAdd(&ctl->num_pos[e / NBOX], pos);

  // block-reduce pos-weighted sums
  float pc = pos * cl, pl = pos * ll;
#pragma unroll
  for (int off = 32; off > 0; off >>= 1) {
    pc += __shfl_down(pc, off);
    pl += __shfl_down(pl, off);
  }
  const int wid = tid >> 6;
  if ((tid & 63) == 0) { sred[wid] = pc; sred[8 + wid] = pl; }
  __syncthreads();   // also orders all LDS hist atomics before the merge below
  if (tid == 0) {
    float a = sred[0] + sred[1] + sred[2] + sred[3];
    float b = sred[8] + sred[9] + sred[10] + sred[11];
    if (a != 0.f) atomicAdd(&ctl->pos_conf_sum, a);
    if (b != 0.f) atomicAdd(&ctl->pos_loc_sum, b);
  }
  for (int i = tid; i < 1024; i += 256)
    if (h[i]) {
      atomicAdd(&ctl->hist[i], h[i]);
      atomicAdd(&ctl->hsum[i], hs[i]);
    }
}

// ---------------------------------------------------------------------------
// Radix-select scan over 2048 bins (L1 populates only [0,1024)):
// suffix-sum counts -> bin of k-th largest; accumulate CL-sum of bins above.
// LEVEL 1 additionally computes k (num_neg_batch) and the denominator.
// ---------------------------------------------------------------------------
template <int LEVEL>
__global__ __launch_bounds__(1024) void k_scan(Ctl* __restrict__ ctl) {
  __shared__ unsigned int s[2048];
  __shared__ float sf[2048];
  __shared__ float red[16];
  __shared__ unsigned int kk;
  __shared__ int win;
  const int tid = threadIdx.x;

  if (LEVEL == 1) {
    float np  = (tid < BATCH) ? ctl->num_pos[tid] : 0.f;
    float nn  = fminf(3.0f * np, (float)NBOX - np);       // 0 for tid>=BATCH
    float hp  = (np > 0.f) ? 1.f : 0.f;
    float npc = (tid < BATCH) ? ((np != 0.f) ? np : 1.f) : 0.f;
#pragma unroll
    for (int off = 32; off > 0; off >>= 1) {
      nn += __shfl_down(nn, off);
      hp += __shfl_down(hp, off);
      npc += __shfl_down(npc, off);
    }
    __shared__ float rn[16], rh[16], rc[16];
    const int wid = tid >> 6;
    if ((tid & 63) == 0) { rn[wid] = nn; rh[wid] = hp; rc[wid] = npc; }
    __syncthreads();
    if (tid == 0) {
      float tn = 0.f, th = 0.f, tc = 0.f;
      for (int i = 0; i < 16; ++i) { tn += rn[i]; th += rh[i]; tc += rc[i]; }
      float knb = (th > 0.f) ? tn : 100.0f;   // NEG_FOR_HARD when no positives
      unsigned int k = (unsigned int)floorf(knb);
      ctl->denom = tc;
      ctl->k_rem = k;
      if (k == 0) ctl->done = 1;
      kk = k;
    }
  } else {
    if (tid == 0) kk = ctl->k_rem;
  }
  if (tid == 0) win = -1;

  s[tid]         = ctl->hist[tid];
  s[tid + 1024]  = ctl->hist[tid + 1024];
  sf[tid]        = ctl->hsum[tid];
  sf[tid + 1024] = ctl->hsum[tid + 1024];
  __syncthreads();

  const unsigned int krem = kk;   // uniform
  if (krem != 0) {
    // inclusive suffix scan (Hillis-Steele), read-phase/write-phase barriered
    for (int off = 1; off < 2048; off <<= 1) {
      unsigned int v0 = (tid + off < 2048) ? s[tid + off] : 0u;
      unsigned int v1 = (tid + 1024 + off < 2048) ? s[tid + 1024 + off] : 0u;
      __syncthreads();
      s[tid] += v0;
      s[tid + 1024] += v1;
      __syncthreads();
    }
    // unique bin b*: suffix[b*] >= k > suffix[b*+1]
#pragma unroll
    for (int t = 0; t < 2; ++t) {
      int i = tid + t * 1024;
      unsigned int si = s[i];
      unsigned int sn = (i < 2047) ? s[i + 1] : 0u;
      if (si >= krem && sn < krem) win = i;
    }
    __syncthreads();
    const int b = win;   // uniform
    // sum CL over bins strictly above b* (fully-selected bins)
    float acc = 0.f;
    if (b >= 0) {
      if (tid > b) acc += sf[tid];
      if (tid + 1024 > b) acc += sf[tid + 1024];
    }
#pragma unroll
    for (int off = 32; off > 0; off >>= 1) acc += __shfl_down(acc, off);
    const int wid = tid >> 6;
    if ((tid & 63) == 0) red[wid] = acc;
    __syncthreads();
    if (tid == 0 && b >= 0) {
      float tot = 0.f;
      for (int i = 0; i < 16; ++i) tot += red[i];
      ctl->s_gt += tot;                    // single-block kernel: plain RMW is safe
      unsigned int above = (b < 2047) ? s[b + 1] : 0u;
      ctl->k_rem = krem - above;           // rank remaining inside bin b
      if (LEVEL == 1)      ctl->prefix = ((unsigned int)b) << 22;
      else if (LEVEL == 2) ctl->prefix |= ((unsigned int)b) << 11;
      else {
        ctl->prefix |= (unsigned int)b;
        ctl->n_eq = s[b] - above;          // ties are bit-identical values
        ctl->s_eq = sf[b];
      }
    }
  }
  __syncthreads();
  ctl->hist[tid] = 0u; ctl->hist[tid + 1024] = 0u;   // re-zero for next level
  ctl->hsum[tid] = 0.f; ctl->hsum[tid + 1024] = 0.f;
}

// ---------------------------------------------------------------------------
// Refinement histograms (count + CL-sum) for radix levels 2 and 3.
// MC/CL are 4.5 MB each -> L2/L3-resident re-reads. float4 streamed.
// ---------------------------------------------------------------------------
template <int LEVEL>
__global__ __launch_bounds__(256) void k_hist(const float* __restrict__ MC,
                                              const float* __restrict__ CL,
                                              Ctl* __restrict__ ctl) {
  __shared__ unsigned int h[2048];
  __shared__ float hs[2048];
  for (int i = threadIdx.x; i < 2048; i += 256) { h[i] = 0u; hs[i] = 0.f; }
  __syncthreads();
  const unsigned int pfx = ctl->prefix;
  const float4* MC4 = (const float4*)MC;
  const float4* CL4 = (const float4*)CL;
  const int n4 = M / 4;
  const int stride = gridDim.x * 256;
  for (int i = blockIdx.x * 256 + threadIdx.x; i < n4; i += stride) {
    const float4 m = MC4[i];
    const float4 cv = CL4[i];
    const float mv[4] = {m.x, m.y, m.z, m.w};
    const float cvv[4] = {cv.x, cv.y, cv.z, cv.w};
#pragma unroll
    for (int j = 0; j < 4; ++j) {
      const unsigned int bits = __float_as_uint(mv[j]);
      bool pass;
      unsigned int bin;
      if (LEVEL == 2) { pass = (bits >> 22) == (pfx >> 22); bin = (bits >> 11) & 0x7FFu; }
      else            { pass = (bits >> 11) == (pfx >> 11); bin = bits & 0x7FFu; }
      if (pass) { atomicAdd(&h[bin], 1u); atomicAdd(&hs[bin], cvv[j]); }
    }
  }
  __syncthreads();
  for (int i = threadIdx.x; i < 2048; i += 256)
    if (h[i]) {
      atomicAdd(&ctl->hist[i], h[i]);
      atomicAdd(&ctl->hsum[i], hs[i]);
    }
}

__global__ void k_combine(Ctl* __restrict__ ctl, float* __restrict__ out) {
  float neg = ctl->s_gt;
  if (ctl->n_eq > 0)
    neg += ctl->s_eq * ((float)ctl->k_rem / (float)ctl->n_eq);
  out[0] = (ctl->pos_conf_sum + neg + ctl->pos_loc_sum) / ctl->denom;
}

// ---------------------------------------------------------------------------
extern "C" void kernel_launch(void* const* d_in, const int* in_sizes, int n_in,
                              void* d_out, int out_size, void* d_ws, size_t ws_size,
                              hipStream_t stream) {
  const float* yt = (const float*)d_in[0];   // y_true    (B,N,26)
  const float* lp = (const float*)d_in[1];   // loc_pred  (B,N,4)
  const float* cp = (const float*)d_in[2];   // conf_pred (B,N,21)
  float* out = (float*)d_out;

  char* ws = (char*)d_ws;
  Ctl* ctl = (Ctl*)ws;                       // sizeof(Ctl) = 16960 < 20480
  float* MC = (float*)(ws + 20480);
  float* CL = MC + M;                        // total ws use ~8.96 MB

  hipMemsetAsync(ctl, 0, sizeof(Ctl), stream);
  k_elem<<<M / 256, 256, 0, stream>>>(yt, lp, cp, MC, CL, ctl);
  k_scan<1><<<1, 1024, 0, stream>>>(ctl);
  k_hist<2><<<1024, 256, 0, stream>>>(MC, CL, ctl);
  k_scan<2><<<1, 1024, 0, stream>>>(ctl);
  k_hist<3><<<1024, 256, 0, stream>>>(MC, CL, ctl);
  k_scan<3><<<1, 1024, 0, stream>>>(ctl);
  k_combine<<<1, 1, 0, stream>>>(ctl, out);
}